// Round 5
// baseline (91.621 us; speedup 1.0000x reference)
//
#include <hip/hip_runtime.h>

// Problem constants (from setup_inputs): N=4096, C=64, A=256
#define N_ROWS 4096
#define C_CLS  64
#define A_DIM  256
#define BK     16           // K-chunk (over b) per block in kernel A
#define KCHUNK (A_DIM / BK) // 16
#define GRID_A (C_CLS * KCHUNK) // 1024 blocks -> 4 blocks/CU on 256 CUs
#define LOSS_BLOCKS 256     // kernel B blocks (4 waves each, 4 rows/wave)

// ---------------------------------------------------------------------------
// Module-global storage (NOT the harness workspace — that gets a 256 MiB
// poison fill every iteration; the fill is LLC-bound at ~44 us and is fixed
// harness overhead). Spart/g_part are written before read every launch; the
// A->B and B->C kernel boundaries provide coherence (runtime flush/inv),
// proven in rounds 0 and 3.
//
// Ledger of failed alternatives (rounds 1-2): in-kernel grid barrier costs
// 30-75 us on this chip (ordered agent atomics sweep per-XCD L2s; even a
// relaxed spin barrier carries ~30 us). Kernel boundaries cost ~1-2 us.
// Ticket-merged finalize (round 3) was neutral-to-worse than a separate
// 1-block finalize kernel. So: three kernels, boundary-synced, no atomics.
// ---------------------------------------------------------------------------
__device__ float g_Spart[KCHUNK * C_CLS * C_CLS]; // 256 KB partial quad-forms
__device__ float g_part[LOSS_BLOCKS];             // per-block loss partials

// ---------------------------------------------------------------------------
// Kernel A: Spart[kc][y][c] = partial over b-chunk of (w_c-w_y)^T CV[y] (w_c-w_y)
// T[c][a] = sum_b D[c][b] * CV[y][b][a]  (CV symmetric -> row reads)
// S[c]    = sum_a D[c][a] * T[c][a]; linear in T so per-chunk partials sum.
// BK=16: 1024 blocks = 4 blocks/CU (was 2) -> stage/compute interleaving
// across 4 resident blocks hides the cold-HBM staging latency that a
// 2-block/CU schedule exposes. Same total FMA + HBM bytes as BK=32.
// ---------------------------------------------------------------------------
__global__ __launch_bounds__(256) void qform_kernel(
    const float* __restrict__ W,      // [C][A]
    const float* __restrict__ CV)     // [C][A][A]
{
    __shared__ float Vt[BK][A_DIM];   // 16 KB : Vt[k][a] = CV[y][kb+k][a]
    __shared__ float Dt[BK][C_CLS];   //  4 KB : Dt[k][c] = W[c][kb+k]-W[y][kb+k]
    __shared__ float Psum[32][C_CLS]; //  8 KB : per-(a-group) partial S

    const int t  = threadIdx.x;
    const int y  = blockIdx.x >> 4;          // blockIdx / KCHUNK
    const int kc = blockIdx.x & 15;          // k-chunk index
    const int kb = kc * BK;                  // b-range start

    // ---- stage Vt: rows kb..kb+BK-1 of CV[y] (contiguous 16 KB, coalesced) ----
    {
        const float4* src = (const float4*)(CV + ((size_t)y * A_DIM * A_DIM
                                                  + (size_t)kb * A_DIM));
        float4* vdst = (float4*)&Vt[0][0];
        #pragma unroll
        for (int i = 0; i < (BK * A_DIM / 4) / 256; ++i)   // 4 iters
            vdst[t + i * 256] = src[t + i * 256];
    }

    // ---- stage Dt (transposed diff chunk): thread t -> c=t>>2, k=(t&3)*4.. ----
    {
        const int kq = (t & 3) * 4;      // k = kq..kq+3
        const int c  = t >> 2;           // 0..63
        const float4 wy = *(const float4*)(W + y * A_DIM + kb + kq);
        const float4 wc = *(const float4*)(W + c * A_DIM + kb + kq);
        Dt[kq + 0][c] = wc.x - wy.x;
        Dt[kq + 1][c] = wc.y - wy.y;
        Dt[kq + 2][c] = wc.z - wy.z;
        Dt[kq + 3][c] = wc.w - wy.w;
    }
    __syncthreads();

    // ---- 8x8 register tile: c0=(t%8)*8 covers 64 c, a0=(t/8)*8 covers 256 a ----
    const int c0 = (t & 7) * 8;
    const int a0 = (t >> 3) * 8;
    float acc[8][8];
    #pragma unroll
    for (int i = 0; i < 8; ++i)
        #pragma unroll
        for (int j = 0; j < 8; ++j) acc[i][j] = 0.0f;

    #pragma unroll 2
    for (int k = 0; k < BK; ++k) {
        const float4 a_lo = *(const float4*)&Vt[k][a0];
        const float4 a_hi = *(const float4*)&Vt[k][a0 + 4];
        const float4 d_lo = *(const float4*)&Dt[k][c0];
        const float4 d_hi = *(const float4*)&Dt[k][c0 + 4];
        const float af[8] = {a_lo.x, a_lo.y, a_lo.z, a_lo.w,
                             a_hi.x, a_hi.y, a_hi.z, a_hi.w};
        const float df[8] = {d_lo.x, d_lo.y, d_lo.z, d_lo.w,
                             d_hi.x, d_hi.y, d_hi.z, d_hi.w};
        #pragma unroll
        for (int i = 0; i < 8; ++i)
            #pragma unroll
            for (int j = 0; j < 8; ++j)
                acc[i][j] += df[i] * af[j];
    }

    // ---- fused epilogue: s_i = sum_j acc[i][j] * (W[c0+i][a0+j] - W[y][a0+j]) ----
    float s[8];
    {
        const float4 wy_lo = *(const float4*)(W + y * A_DIM + a0);
        const float4 wy_hi = *(const float4*)(W + y * A_DIM + a0 + 4);
        const float wyv[8] = {wy_lo.x, wy_lo.y, wy_lo.z, wy_lo.w,
                              wy_hi.x, wy_hi.y, wy_hi.z, wy_hi.w};
        #pragma unroll
        for (int i = 0; i < 8; ++i) {
            const int c = c0 + i;
            const float4 wc_lo = *(const float4*)(W + c * A_DIM + a0);
            const float4 wc_hi = *(const float4*)(W + c * A_DIM + a0 + 4);
            const float wcv[8] = {wc_lo.x, wc_lo.y, wc_lo.z, wc_lo.w,
                                  wc_hi.x, wc_hi.y, wc_hi.z, wc_hi.w};
            float ss = 0.0f;
            #pragma unroll
            for (int j = 0; j < 8; ++j)
                ss += acc[i][j] * (wcv[j] - wyv[j]);
            s[i] = ss;
        }
    }
    // conflict-free staging: 8 consecutive floats per thread (2x ds_write_b128)
    const int ag = t >> 3;   // a-group 0..31
    *(float4*)&Psum[ag][c0]     = make_float4(s[0], s[1], s[2], s[3]);
    *(float4*)&Psum[ag][c0 + 4] = make_float4(s[4], s[5], s[6], s[7]);
    __syncthreads();

    if (t < C_CLS) {
        float r = 0.0f;
        #pragma unroll
        for (int g = 0; g < 32; ++g) r += Psum[g][t];   // stride-1 across lanes
        g_Spart[kc * C_CLS * C_CLS + y * C_CLS + t] = r;
    }
}

// ---------------------------------------------------------------------------
// Kernel B: per-row softmax CE on aug = pred + 0.5*Lambda*sum_k Spart[k][y].
// One wave per row, 4 waves/block, 4 rows per wave; per-block partial to
// g_part. Round-0-proven structure; only KCHUNK changed (8 -> 16 partials,
// independent L2-hot loads).
// ---------------------------------------------------------------------------
__global__ __launch_bounds__(256) void loss_kernel(
    const float* __restrict__ pred,    // [N][C]
    const int*   __restrict__ labels,  // [N]
    const float* __restrict__ lambda_p)
{
    __shared__ float wsum[4];
    const int t    = threadIdx.x;
    const int lane = t & 63;
    const int wgid = blockIdx.x * 4 + (t >> 6);   // global wave id, 0..1023
    const float lam = 0.5f * lambda_p[0];

    float acc_nll = 0.0f;
    #pragma unroll
    for (int r = 0; r < 4; ++r) {
        const int n = r * 1024 + wgid;
        const int y = labels[n];
        float sp = 0.0f;
        #pragma unroll
        for (int k = 0; k < KCHUNK; ++k)
            sp += g_Spart[k * C_CLS * C_CLS + y * C_CLS + lane];
        const float logit = pred[n * C_CLS + lane] + lam * sp;

        float m = logit;
        #pragma unroll
        for (int off = 32; off > 0; off >>= 1)
            m = fmaxf(m, __shfl_xor(m, off, 64));
        float e = __expf(logit - m);
        float ssum = e;
        #pragma unroll
        for (int off = 32; off > 0; off >>= 1)
            ssum += __shfl_xor(ssum, off, 64);
        const float ly = __shfl(logit, y, 64);
        acc_nll += logf(ssum) + m - ly;
    }

    if (lane == 0) wsum[t >> 6] = acc_nll;
    __syncthreads();
    if (t == 0)
        g_part[blockIdx.x] = wsum[0] + wsum[1] + wsum[2] + wsum[3];
}

// ---------------------------------------------------------------------------
// Kernel C: reduce 256 block partials -> mean loss. One block.
// ---------------------------------------------------------------------------
__global__ __launch_bounds__(256) void finalize_kernel(float* __restrict__ out)
{
    __shared__ float wsum[4];
    const int t = threadIdx.x;
    float v = g_part[t];
    #pragma unroll
    for (int off = 32; off > 0; off >>= 1)
        v += __shfl_xor(v, off, 64);
    if ((t & 63) == 0) wsum[t >> 6] = v;
    __syncthreads();
    if (t == 0)
        out[0] = (wsum[0] + wsum[1] + wsum[2] + wsum[3]) * (1.0f / (float)N_ROWS);
}

// ---------------------------------------------------------------------------
extern "C" void kernel_launch(void* const* d_in, const int* in_sizes, int n_in,
                              void* d_out, int out_size, void* d_ws, size_t ws_size,
                              hipStream_t stream) {
    (void)in_sizes; (void)n_in; (void)out_size; (void)d_ws; (void)ws_size;
    const float* W      = (const float*)d_in[0];   // fc_weight [64][256]
    // d_in[1] = features (unused by the reference computation)
    const float* pred   = (const float*)d_in[2];   // [4096][64]
    const int*   labels = (const int*)d_in[3];     // [4096]
    const float* lam    = (const float*)d_in[4];   // scalar
    const float* CV     = (const float*)d_in[5];   // [64][256][256]
    float* out = (float*)d_out;

    qform_kernel<<<dim3(GRID_A), dim3(256), 0, stream>>>(W, CV);
    loss_kernel<<<dim3(LOSS_BLOCKS), dim3(256), 0, stream>>>(pred, labels, lam);
    finalize_kernel<<<dim3(1), dim3(256), 0, stream>>>(out);
}

// Round 6
// 89.877 us; speedup vs baseline: 1.0194x; 1.0194x over previous
//
#include <hip/hip_runtime.h>

// Problem constants (from setup_inputs): N=4096, C=64, A=256
#define N_ROWS 4096
#define C_CLS  64
#define A_DIM  256
#define BK     32           // K-chunk (over b) per block in kernel A
#define KCHUNK (A_DIM / BK) // 8
#define LOSS_BLOCKS 256     // kernel B blocks (4 waves each, 4 rows/wave)

// ---------------------------------------------------------------------------
// Session ledger (rounds 0-5):
//  - fixed harness overhead ≈ 62 us (256 MiB ws poison fill ~44 us, LLC-write
//    bound, + ~18 us of tiny reset dispatches). Untouchable.
//  - in-kernel grid barriers: 30-75 us on this chip (rounds 1-2) — dead end.
//  - kernel boundaries are cheap; ticket-merged finalize neutral-to-worse.
//  - BK 32->16 (2->4 blocks/CU): neutral — A is not latency/occupancy-bound.
//  - round 1 counter row: qform code at VGPR_Count=72 with an 8x8 fp32 acc
//    (64 regs) + operands -> accumulator was placed in AGPRs (gfx950 unified
//    file). Non-MFMA math on AGPR-resident values costs accvgpr_read/fma/
//    accvgpr_write = ~3x inner-loop issue -> explains A ~3x over VALU floor.
//  THIS ROUND: 512-thread blocks with a 4x8 per-thread tile (acc = 32 VGPR,
//  ~80 total) so the accumulator stays in arch VGPRs. Same FLOPs, same bytes.
//  B/C/d_ws placement are round-0 verbatim (measured best: 88.8 us).
// ---------------------------------------------------------------------------

// ---------------------------------------------------------------------------
// Kernel A: Spart[kc][y][c] = partial over b-chunk of (w_c-w_y)^T CV[y] (w_c-w_y)
// T[c][a] = sum_b D[c][b] * CV[y][b][a]  (CV symmetric -> row reads)
// S[c]    = sum_a D[c][a] * T[c][a]; linear in T so per-chunk partials sum.
// grid = 64*KCHUNK = 512 blocks of 512 threads (2 blocks/CU, 48 KB LDS).
// ---------------------------------------------------------------------------
__global__ __launch_bounds__(512) void qform_kernel(
    const float* __restrict__ W,      // [C][A]
    const float* __restrict__ CV,     // [C][A][A]
    float* __restrict__ Spart)        // [KCHUNK][C][C]
{
    __shared__ float Vt[BK][A_DIM];   // 32 KB : Vt[k][a] = CV[y][kb+k][a]
    __shared__ float Dt[BK][C_CLS];   //  8 KB : Dt[k][c] = W[c][kb+k]-W[y][kb+k]
    __shared__ float Psum[32][C_CLS]; //  8 KB : per-(a-group) partial S

    const int t  = threadIdx.x;              // 0..511
    const int y  = blockIdx.x >> 3;          // blockIdx / KCHUNK
    const int kc = blockIdx.x & 7;           // k-chunk index
    const int kb = kc * BK;                  // b-range start

    // ---- stage Vt: rows kb..kb+BK-1 of CV[y] (contiguous 32 KB, coalesced) ----
    {
        const float4* src = (const float4*)(CV + ((size_t)y * A_DIM * A_DIM
                                                  + (size_t)kb * A_DIM));
        float4* vdst = (float4*)&Vt[0][0];
        #pragma unroll
        for (int i = 0; i < (BK * A_DIM / 4) / 512; ++i)   // 4 iters
            vdst[t + i * 512] = src[t + i * 512];
    }

    // ---- stage Dt (transposed diff chunk): t -> c=t>>3 (0..63), kq=(t&7)*4 ----
    {
        const int kq = (t & 7) * 4;      // k = kq..kq+3
        const int c  = t >> 3;           // 0..63
        const float4 wy = *(const float4*)(W + y * A_DIM + kb + kq);
        const float4 wc = *(const float4*)(W + c * A_DIM + kb + kq);
        Dt[kq + 0][c] = wc.x - wy.x;
        Dt[kq + 1][c] = wc.y - wy.y;
        Dt[kq + 2][c] = wc.z - wy.z;
        Dt[kq + 3][c] = wc.w - wy.w;
    }
    __syncthreads();

    // ---- 4x8 register tile: c0=(t%16)*4 covers 64 c, a0=(t/16)*8 covers 256 a.
    // acc = 32 VGPR -> stays in arch VGPRs (the whole point of this round).
    // LDS reads are broadcast-heavy: 16 lanes share each Vt address, 4 lanes
    // share each Dt address -> conflict-free.
    const int c0 = (t & 15) * 4;
    const int a0 = (t >> 4) * 8;
    float acc[4][8];
    #pragma unroll
    for (int i = 0; i < 4; ++i)
        #pragma unroll
        for (int j = 0; j < 8; ++j) acc[i][j] = 0.0f;

    #pragma unroll 4
    for (int k = 0; k < BK; ++k) {
        const float4 a_lo = *(const float4*)&Vt[k][a0];
        const float4 a_hi = *(const float4*)&Vt[k][a0 + 4];
        const float4 d    = *(const float4*)&Dt[k][c0];
        const float af[8] = {a_lo.x, a_lo.y, a_lo.z, a_lo.w,
                             a_hi.x, a_hi.y, a_hi.z, a_hi.w};
        const float df[4] = {d.x, d.y, d.z, d.w};
        #pragma unroll
        for (int i = 0; i < 4; ++i)
            #pragma unroll
            for (int j = 0; j < 8; ++j)
                acc[i][j] += df[i] * af[j];
    }

    // ---- fused epilogue: s_i = sum_j acc[i][j] * (W[c0+i][a0+j] - W[y][a0+j]) ----
    float s[4];
    {
        const float4 wy_lo = *(const float4*)(W + y * A_DIM + a0);
        const float4 wy_hi = *(const float4*)(W + y * A_DIM + a0 + 4);
        const float wyv[8] = {wy_lo.x, wy_lo.y, wy_lo.z, wy_lo.w,
                              wy_hi.x, wy_hi.y, wy_hi.z, wy_hi.w};
        #pragma unroll
        for (int i = 0; i < 4; ++i) {
            const int c = c0 + i;
            const float4 wc_lo = *(const float4*)(W + c * A_DIM + a0);
            const float4 wc_hi = *(const float4*)(W + c * A_DIM + a0 + 4);
            const float wcv[8] = {wc_lo.x, wc_lo.y, wc_lo.z, wc_lo.w,
                                  wc_hi.x, wc_hi.y, wc_hi.z, wc_hi.w};
            float ss = 0.0f;
            #pragma unroll
            for (int j = 0; j < 8; ++j)
                ss += acc[i][j] * (wcv[j] - wyv[j]);
            s[i] = ss;
        }
    }
    // conflict-free staging: one contiguous float4 per thread (1 KB/wave)
    const int ag = t >> 4;   // a-group 0..31
    *(float4*)&Psum[ag][c0] = make_float4(s[0], s[1], s[2], s[3]);
    __syncthreads();

    if (t < C_CLS) {
        float r = 0.0f;
        #pragma unroll
        for (int g = 0; g < 32; ++g) r += Psum[g][t];   // stride-1 across lanes
        Spart[(size_t)kc * C_CLS * C_CLS + y * C_CLS + t] = r;
    }
}

// ---------------------------------------------------------------------------
// Kernel B: per-row softmax CE on aug = pred + 0.5*Lambda*sum_k Spart[k][y].
// One wave per row, 4 waves/block, 4 rows per wave; per-block partial to ws.
// Round-0 verbatim (measured best tail).
// ---------------------------------------------------------------------------
__global__ __launch_bounds__(256) void loss_kernel(
    const float* __restrict__ pred,    // [N][C]
    const int*   __restrict__ labels,  // [N]
    const float* __restrict__ lambda_p,
    const float* __restrict__ Spart,   // [KCHUNK][C][C]
    float* __restrict__ partials)      // [LOSS_BLOCKS]
{
    __shared__ float wsum[4];
    const int t    = threadIdx.x;
    const int lane = t & 63;
    const int wgid = blockIdx.x * 4 + (t >> 6);   // global wave id, 0..1023
    const float lam = 0.5f * lambda_p[0];

    float acc_nll = 0.0f;
    #pragma unroll
    for (int r = 0; r < 4; ++r) {
        const int n = r * 1024 + wgid;
        const int y = labels[n];
        float sp = 0.0f;
        #pragma unroll
        for (int k = 0; k < KCHUNK; ++k)
            sp += Spart[(size_t)k * C_CLS * C_CLS + y * C_CLS + lane];
        const float logit = pred[n * C_CLS + lane] + lam * sp;

        float m = logit;
        #pragma unroll
        for (int off = 32; off > 0; off >>= 1)
            m = fmaxf(m, __shfl_xor(m, off, 64));
        float e = __expf(logit - m);
        float ssum = e;
        #pragma unroll
        for (int off = 32; off > 0; off >>= 1)
            ssum += __shfl_xor(ssum, off, 64);
        const float ly = __shfl(logit, y, 64);
        acc_nll += logf(ssum) + m - ly;
    }

    if (lane == 0) wsum[t >> 6] = acc_nll;
    __syncthreads();
    if (t == 0)
        partials[blockIdx.x] = wsum[0] + wsum[1] + wsum[2] + wsum[3];
}

// ---------------------------------------------------------------------------
// Kernel C: reduce 256 block partials -> mean loss. One block. Round-0 verbatim.
// ---------------------------------------------------------------------------
__global__ __launch_bounds__(256) void finalize_kernel(
    const float* __restrict__ partials, float* __restrict__ out)
{
    __shared__ float wsum[4];
    const int t = threadIdx.x;
    float v = partials[t];
    #pragma unroll
    for (int off = 32; off > 0; off >>= 1)
        v += __shfl_xor(v, off, 64);
    if ((t & 63) == 0) wsum[t >> 6] = v;
    __syncthreads();
    if (t == 0)
        out[0] = (wsum[0] + wsum[1] + wsum[2] + wsum[3]) * (1.0f / (float)N_ROWS);
}

// ---------------------------------------------------------------------------
extern "C" void kernel_launch(void* const* d_in, const int* in_sizes, int n_in,
                              void* d_out, int out_size, void* d_ws, size_t ws_size,
                              hipStream_t stream) {
    (void)in_sizes; (void)n_in; (void)out_size; (void)ws_size;
    const float* W      = (const float*)d_in[0];   // fc_weight [64][256]
    // d_in[1] = features (unused by the reference computation)
    const float* pred   = (const float*)d_in[2];   // [4096][64]
    const int*   labels = (const int*)d_in[3];     // [4096]
    const float* lam    = (const float*)d_in[4];   // scalar
    const float* CV     = (const float*)d_in[5];   // [64][256][256]
    float* out = (float*)d_out;

    float* Spart    = (float*)d_ws;                             // 8*64*64 floats = 128 KB
    float* partials = (float*)d_ws + KCHUNK * C_CLS * C_CLS;    // 256 floats

    qform_kernel<<<dim3(C_CLS * KCHUNK), dim3(512), 0, stream>>>(W, CV, Spart);
    loss_kernel<<<dim3(LOSS_BLOCKS), dim3(256), 0, stream>>>(pred, labels, lam, Spart, partials);
    finalize_kernel<<<dim3(1), dim3(256), 0, stream>>>(partials, out);
}